// Round 2
// baseline (361.877 us; speedup 1.0000x reference)
//
#include <hip/hip_runtime.h>
#include <math.h>

// Problem constants (match reference)
constexpr int B    = 4;
constexpr int N    = 32768;   // 2^15
constexpr int K    = 16;
constexpr int CIN  = 32;
constexpr int H    = 32;
constexpr int COUT = 32;
constexpr int NODES = B * N;          // 131072
constexpr int E      = B * N * K;     // 2097152 edges

// ---------------------------------------------------------------------------
// Kernel 1: fc1 + fold grid_weight and gaussian normalizer into hh[node][h]
//   hh[node,h] = coef[h] * gw[node] * (sum_c x[b,c,n]*W1[h,c] + b1[h])
//   coef[h] = sqrt((bw[h]/pi)^3)
// ---------------------------------------------------------------------------
__global__ __launch_bounds__(256) void k_fc1(const float* __restrict__ x,
                                             const float* __restrict__ grid_weight,
                                             const float* __restrict__ W1,
                                             const float* __restrict__ b1,
                                             const float* __restrict__ baseweight,
                                             float* __restrict__ hh)
{
    __shared__ float sW1[H * CIN];
    __shared__ float sb1[H];
    __shared__ float scoef[H];
    const int tid = threadIdx.x;
    for (int i = tid; i < H * CIN; i += 256) sW1[i] = W1[i];
    if (tid < H) {
        sb1[tid] = b1[tid];
        float t = baseweight[tid] * (float)(1.0 / M_PI);
        scoef[tid] = t * sqrtf(t);           // (bw/pi)^1.5 == sqrt((bw/pi)^3)
    }
    __syncthreads();

    const int node = blockIdx.x * 256 + tid;  // [0, NODES)
    const int b = node >> 15;                 // node / N
    const int n = node & (N - 1);
    const float* xb = x + (size_t)b * CIN * N + n;

    float acc[H];
#pragma unroll
    for (int h = 0; h < H; ++h) acc[h] = sb1[h];
#pragma unroll
    for (int c = 0; c < CIN; ++c) {
        float xv = xb[(size_t)c * N];         // coalesced across threads
#pragma unroll
        for (int h = 0; h < H; ++h) acc[h] = fmaf(xv, sW1[h * CIN + c], acc[h]);
    }
    const float gw = grid_weight[node];

    float4* dst = (float4*)(hh + (size_t)node * H);
#pragma unroll
    for (int i = 0; i < H / 4; ++i) {
        float4 v;
        v.x = acc[4 * i + 0] * gw * scoef[4 * i + 0];
        v.y = acc[4 * i + 1] * gw * scoef[4 * i + 1];
        v.z = acc[4 * i + 2] * gw * scoef[4 * i + 2];
        v.w = acc[4 * i + 3] * gw * scoef[4 * i + 3];
        dst[i] = v;
    }
}

// ---------------------------------------------------------------------------
// Kernel 2: per-edge gaussian weight + scatter-add.
// 32 threads per edge: lane h handles channel h. hh gather and atomicAdd are
// contiguous 128B per half-wave.
// ---------------------------------------------------------------------------
__global__ __launch_bounds__(256) void k_edge(const float* __restrict__ grid,
                                              const int* __restrict__ esrc,
                                              const int* __restrict__ edst,
                                              const float* __restrict__ baseweight,
                                              const float* __restrict__ hh,
                                              float* __restrict__ acc)
{
    __shared__ float sbw[H];
    sbw[threadIdx.x & 31] = baseweight[threadIdx.x & 31];  // wave-uniform init
    __syncthreads();

    const int t = blockIdx.x * 256 + threadIdx.x;
    const int e = t >> 5;          // edge id [0, E)
    const int h = t & 31;
    const int b = e >> 19;         // e / (N*K)   (N*K = 2^19)
    const int boff = b * N;
    const int s = esrc[e] + boff;  // broadcast load within half-wave
    const int d = edst[e] + boff;

    const float dx = grid[s * 3 + 0] - grid[d * 3 + 0];
    const float dy = grid[s * 3 + 1] - grid[d * 3 + 1];
    const float dz = grid[s * 3 + 2] - grid[d * 3 + 2];
    const float d2 = dx * dx + dy * dy + dz * dz;

    const float v = __expf(-sbw[h] * d2) * hh[(size_t)s * H + h];
    atomicAdd(&acc[(size_t)d * H + h], v);
}

// ---------------------------------------------------------------------------
// Kernel 3: fc2 + output transpose.
//   out[b, o, n] = sum_h acc[node,h] * W2[o,h] + b2[o]
// Coalesced acc read staged through padded LDS; coalesced out store.
// ---------------------------------------------------------------------------
__global__ __launch_bounds__(256) void k_fc2(const float* __restrict__ acc,
                                             const float* __restrict__ W2,
                                             const float* __restrict__ b2,
                                             float* __restrict__ out)
{
    __shared__ float sW2[COUT * H];
    __shared__ float sb2[COUT];
    __shared__ float stage[256 * (H + 1)];   // +1 pad: conflict-free row reads
    const int tid = threadIdx.x;
    for (int i = tid; i < COUT * H; i += 256) sW2[i] = W2[i];
    if (tid < COUT) sb2[tid] = b2[tid];

    // cooperative coalesced load of 256 nodes x 32 ch
    const size_t base = (size_t)blockIdx.x * 256 * H;
#pragma unroll
    for (int i = 0; i < 32; ++i) {
        int f = i * 256 + tid;
        stage[(f >> 5) * (H + 1) + (f & 31)] = acc[base + f];
    }
    __syncthreads();

    float row[H];
#pragma unroll
    for (int h = 0; h < H; ++h) row[h] = stage[tid * (H + 1) + h];

    const int node = blockIdx.x * 256 + tid;
    const int b = node >> 15;
    const int n = node & (N - 1);
    float* ob = out + (size_t)b * COUT * N + n;

#pragma unroll
    for (int o = 0; o < COUT; ++o) {
        float s = sb2[o];
#pragma unroll
        for (int h = 0; h < H; ++h) s = fmaf(row[h], sW2[o * H + h], s);
        ob[(size_t)o * N] = s;   // coalesced across threads
    }
}

// ---------------------------------------------------------------------------
extern "C" void kernel_launch(void* const* d_in, const int* in_sizes, int n_in,
                              void* d_out, int out_size, void* d_ws, size_t ws_size,
                              hipStream_t stream)
{
    const float* x    = (const float*)d_in[0];
    const float* grid = (const float*)d_in[1];
    const float* gw   = (const float*)d_in[2];
    const int*   es   = (const int*)d_in[3];
    const int*   ed   = (const int*)d_in[4];
    const float* W1   = (const float*)d_in[5];
    const float* b1   = (const float*)d_in[6];
    const float* W2   = (const float*)d_in[7];
    const float* b2   = (const float*)d_in[8];
    const float* bw   = (const float*)d_in[9];
    float* out = (float*)d_out;

    float* hh  = (float*)d_ws;                       // NODES*H floats = 16 MB
    float* acc = hh + (size_t)NODES * H;             // NODES*H floats = 16 MB

    hipMemsetAsync(acc, 0, (size_t)NODES * H * sizeof(float), stream);

    k_fc1<<<NODES / 256, 256, 0, stream>>>(x, gw, W1, b1, bw, hh);

    const int edge_blocks = E / 8;                   // 32 thr/edge, 8 edges/block
    k_edge<<<edge_blocks, 256, 0, stream>>>(grid, es, ed, bw, hh, acc);

    k_fc2<<<NODES / 256, 256, 0, stream>>>(acc, W2, b2, out);
}